// Round 9
// baseline (423.758 us; speedup 1.0000x reference)
//
#include <hip/hip_runtime.h>
#include <hip/hip_bf16.h>
#include <math.h>

#define T_TOKENS 2048
#define HID 1024
#define INTER 2048
#define NE 8

typedef __attribute__((ext_vector_type(8))) __bf16 bf16x8;
typedef __attribute__((ext_vector_type(4))) __bf16 bf16x4;
typedef __attribute__((ext_vector_type(4))) float f32x4;

// ---------------- workspace layout (bytes) ----------------
#define WS_COUNTS   0u          // int[8]
#define WS_OFFSETS  64u         // int[8]
#define WS_SEL      128u        // int[4096]
#define WS_SELW     16512u      // float[4096]
#define WS_ROWTOK   32896u      // int[4096]
#define WS_ROWW     49280u      // float[4096]
#define WS_XB       131072u                      // bf16[2048*1024]  (4 MB)
#define WS_Y        (131072u + 4194304u)         // bf16[4096*2048]  (16.8 MB)

// async global->LDS, 16B per lane
__device__ __forceinline__ void gload_lds16(const void* g, void* l) {
    __builtin_amdgcn_global_load_lds(
        (const __attribute__((address_space(1))) unsigned int*)g,
        (__attribute__((address_space(3))) unsigned int*)l, 16, 0, 0);
}

__device__ __forceinline__ bf16x8 cvt8(float4 a, float4 b) {
    bf16x8 r;
    r[0] = (__bf16)a.x; r[1] = (__bf16)a.y; r[2] = (__bf16)a.z; r[3] = (__bf16)a.w;
    r[4] = (__bf16)b.x; r[5] = (__bf16)b.y; r[6] = (__bf16)b.z; r[7] = (__bf16)b.w;
    return r;
}

// BK=32 LDS tile: row-major [rows][32] bf16, 64B rows, 4x 16B granules/row.
// Conflict model (m214/G4): conflict unit = 16B slot mod 128B line; slot(row,p)
// = (4*row + p) mod 8. Unswizzled fragment reads (16 consecutive rows, fixed
// granule) hit 2 slots -> 8-way. Swizzle p = g ^ ((row>>1)&3) makes the 16-row
// read enumerate all 8 slots x2 lanes (2-way = free, m136).
__device__ __forceinline__ bf16x8 ldsfrag(const __bf16* base, int row, int g) {
    return *(const bf16x8*)((const char*)base + row * 64 +
                            ((g ^ ((row >> 1) & 3)) << 4));
}

// ---------------- router (exact fp32) + fused x->bf16 conversion ----------------
__global__ __launch_bounds__(256) void moe_router(
    const float* __restrict__ x, const float* __restrict__ rw,
    int* __restrict__ counts, int* __restrict__ sel, float* __restrict__ selw,
    __bf16* __restrict__ xb)
{
    int wave = threadIdx.x >> 6;
    int lane = threadIdx.x & 63;
    int t = blockIdx.x * 4 + wave;
    if (t >= T_TOKENS) return;

    const float4* x4  = (const float4*)x + (size_t)t * (HID / 4);
    const float4* rw4 = (const float4*)rw;

    float acc[NE];
#pragma unroll
    for (int e = 0; e < NE; ++e) acc[e] = 0.f;
#pragma unroll
    for (int q = 0; q < 4; ++q) {
        int idx = q * 64 + lane;
        float4 xv = x4[idx];
        bf16x4 c;
        c[0] = (__bf16)xv.x; c[1] = (__bf16)xv.y; c[2] = (__bf16)xv.z; c[3] = (__bf16)xv.w;
        *(bf16x4*)(xb + (size_t)t * HID + idx * 4) = c;
#pragma unroll
        for (int e = 0; e < NE; ++e) {
            float4 rv = rw4[e * (HID / 4) + idx];
            acc[e] += xv.x * rv.x + xv.y * rv.y + xv.z * rv.z + xv.w * rv.w;
        }
    }
#pragma unroll
    for (int off = 32; off; off >>= 1)
#pragma unroll
        for (int e = 0; e < NE; ++e) acc[e] += __shfl_xor(acc[e], off, 64);

    if (lane == 0) {
        float m = acc[0];
#pragma unroll
        for (int e = 1; e < NE; ++e) m = fmaxf(m, acc[e]);
        float p[NE], s = 0.f;
#pragma unroll
        for (int e = 0; e < NE; ++e) { p[e] = expf(acc[e] - m); s += p[e]; }
        float inv = 1.f / s;
        int i0 = 0;
#pragma unroll
        for (int e = 1; e < NE; ++e) if (p[e] > p[i0]) i0 = e;
        int i1 = (i0 == 0) ? 1 : 0;
#pragma unroll
        for (int e = 0; e < NE; ++e) if (e != i0 && p[e] > p[i1]) i1 = e;
        sel[t * 2 + 0] = i0; selw[t * 2 + 0] = p[i0] * inv;
        sel[t * 2 + 1] = i1; selw[t * 2 + 1] = p[i1] * inv;
        atomicAdd(&counts[i0], 1);
        atomicAdd(&counts[i1], 1);
    }
}

// ---------------- fused scan + slot assignment (single block) ----------------
__global__ __launch_bounds__(256) void moe_scan_assign(
    const int* __restrict__ counts, int* __restrict__ offsets,
    const int* __restrict__ sel, const float* __restrict__ selw,
    int* __restrict__ row_token, float* __restrict__ row_w)
{
    __shared__ int soff[NE];
    __shared__ int scur[NE];
    if (threadIdx.x == 0) {
        int off = 0;
        for (int e = 0; e < NE; ++e) { soff[e] = off; off += counts[e]; }
    }
    if (threadIdx.x < NE) scur[threadIdx.x] = 0;
    __syncthreads();
    if (threadIdx.x < NE) offsets[threadIdx.x] = soff[threadIdx.x];
    for (int t = threadIdx.x; t < T_TOKENS; t += 256) {
#pragma unroll
        for (int k = 0; k < 2; ++k) {
            int e = sel[t * 2 + k];
            int slot = atomicAdd(&scur[e], 1);
            int r = soff[e] + slot;
            row_token[r] = t;
            row_w[r] = selw[t * 2 + k];
        }
    }
}

// ---------------- GEMM1 (bf16 MFMA, BK=32 dbuf, swizzled): y = silu(.)*(.)-----
// tile 128x64 DUAL (gate+up). LDS 32KB -> 4 blocks/CU. 4 waves as 2x2.
__global__ __launch_bounds__(256, 4) void moe_gemm1(
    const __bf16* __restrict__ xb, const float* __restrict__ w1,
    const int* __restrict__ row_token, const int* __restrict__ counts,
    const int* __restrict__ offsets, __bf16* __restrict__ y)
{
    int e = blockIdx.z;
    int cnt = counts[e];
    int row0 = blockIdx.y * 128;
    if (row0 >= cnt) return;
    int col0 = blockIdx.x * 64;
    int base = offsets[e];

    __shared__ __bf16 As[2][128 * 32];
    __shared__ __bf16 Bg[2][64 * 32];
    __shared__ __bf16 Bu[2][64 * 32];

    int tid = threadIdx.x;
    int lane = tid & 63;
    int wid = tid >> 6;
    int gq = tid & 3;               // granule within 64B row
    int sw = (tid >> 3) & 3;        // s(row) for row = tid>>2 (and +64: same)

    // A staging: gload_lds, linear LDS dest (tid*16) + INVERSE-swizzled source:
    // physical granule gq at row tid>>2 must hold logical granule gq^sw (rule #21).
    const __bf16* srcA[2];
    int dstA[2];
#pragma unroll
    for (int i = 0; i < 2; ++i) {
        int r = i * 64 + (tid >> 2);
        int rl = row0 + r; if (rl > cnt - 1) rl = cnt - 1;
        int tok = row_token[base + rl];
        srcA[i] = xb + (size_t)tok * HID + ((gq ^ sw) << 3);
        dstA[i] = i * 4096 + tid * 16;
    }
    // B staging: reg-stage fp32 (logical granule gq) -> cvt -> SWIZZLED ds_write
    int rb = tid >> 2;
    const float* srcBg = w1 + ((size_t)e * 2 * INTER + col0 + rb) * HID + (gq << 3);
    const float* srcBu = srcBg + (size_t)INTER * HID;
    int offB = rb * 64 + ((gq ^ sw) << 4);

    // ---- prologue: stage k-tile 0 into buffer 0 ----
#pragma unroll
    for (int i = 0; i < 2; ++i) gload_lds16(srcA[i], (char*)As[0] + dstA[i]);
    {
        float4 g0 = *(const float4*)(srcBg);
        float4 g1 = *(const float4*)(srcBg + 4);
        float4 u0 = *(const float4*)(srcBu);
        float4 u1 = *(const float4*)(srcBu + 4);
        *(bf16x8*)((char*)Bg[0] + offB) = cvt8(g0, g1);
        *(bf16x8*)((char*)Bu[0] + offB) = cvt8(u0, u1);
    }
    __syncthreads();

    int wr = (wid >> 1) * 64, wc = (wid & 1) * 32;
    f32x4 ag[4][2] = {}, au[4][2] = {};

    for (int t = 0; t < 32; ++t) {
        int cur = t & 1;
        float4 g0, g1, u0, u1;
        bool pre = (t < 31);
        if (pre) {
            int k0 = (t + 1) * 32;
#pragma unroll
            for (int i = 0; i < 2; ++i)
                gload_lds16(srcA[i] + k0, (char*)As[cur ^ 1] + dstA[i]);
            g0 = *(const float4*)(srcBg + k0);
            g1 = *(const float4*)(srcBg + k0 + 4);
            u0 = *(const float4*)(srcBu + k0);
            u1 = *(const float4*)(srcBu + k0 + 4);
        }
        const __bf16* Ab = As[cur];
        const __bf16* Bgb = Bg[cur];
        const __bf16* Bub = Bu[cur];
        {
            int kg = lane >> 4;
            bf16x8 a[4], bg[2], bu[2];
#pragma unroll
            for (int m = 0; m < 4; ++m) a[m] = ldsfrag(Ab, wr + m * 16 + (lane & 15), kg);
#pragma unroll
            for (int n = 0; n < 2; ++n) {
                bg[n] = ldsfrag(Bgb, wc + n * 16 + (lane & 15), kg);
                bu[n] = ldsfrag(Bub, wc + n * 16 + (lane & 15), kg);
            }
#pragma unroll
            for (int m = 0; m < 4; ++m)
#pragma unroll
                for (int n = 0; n < 2; ++n) {
                    ag[m][n] = __builtin_amdgcn_mfma_f32_16x16x32_bf16(a[m], bg[n], ag[m][n], 0, 0, 0);
                    au[m][n] = __builtin_amdgcn_mfma_f32_16x16x32_bf16(a[m], bu[n], au[m][n], 0, 0, 0);
                }
        }
        if (pre) {
            *(bf16x8*)((char*)Bg[cur ^ 1] + offB) = cvt8(g0, g1);
            *(bf16x8*)((char*)Bu[cur ^ 1] + offB) = cvt8(u0, u1);
        }
        __syncthreads();
    }

    // epilogue: silu(g)*u -> bf16 y.  D layout: col=lane&15, row=(lane>>4)*4+j
#pragma unroll
    for (int m = 0; m < 4; ++m) {
#pragma unroll
        for (int j = 0; j < 4; ++j) {
            int rl = wr + m * 16 + ((lane >> 4) << 2) + j;
            if (row0 + rl >= cnt) continue;
            size_t yrow = (size_t)(base + row0 + rl) * INTER;
#pragma unroll
            for (int n = 0; n < 2; ++n) {
                float g = ag[m][n][j], u = au[m][n][j];
                float s = g / (1.f + __expf(-g));
                y[yrow + col0 + wc + n * 16 + (lane & 15)] = (__bf16)(s * u);
            }
        }
    }
}

// ---------------- GEMM2 (bf16 MFMA, BK=32 dbuf, swizzled, split-K=2, fused) ----
// tile 128x64, blockIdx.y = rowtile*2 + khalf. atomicAdd into out (4 adds/elem).
__global__ __launch_bounds__(256, 4) void moe_gemm2(
    const __bf16* __restrict__ y, const float* __restrict__ w2,
    const float* __restrict__ row_w, const int* __restrict__ row_token,
    const int* __restrict__ counts, const int* __restrict__ offsets,
    float* __restrict__ out)
{
    int e = blockIdx.z;
    int cnt = counts[e];
    int row0 = (blockIdx.y >> 1) * 128;
    if (row0 >= cnt) return;
    int kbase = (blockIdx.y & 1) * (INTER / 2);
    int col0 = blockIdx.x * 64;
    int base = offsets[e];

    __shared__ __bf16 As[2][128 * 32];
    __shared__ __bf16 Bs[2][64 * 32];

    int tid = threadIdx.x;
    int lane = tid & 63;
    int wid = tid >> 6;
    int gq = tid & 3;
    int sw = (tid >> 3) & 3;

    const __bf16* srcA[2];
    int dstA[2];
#pragma unroll
    for (int i = 0; i < 2; ++i) {
        int r = i * 64 + (tid >> 2);
        int rl = row0 + r; if (rl > cnt - 1) rl = cnt - 1;
        srcA[i] = y + (size_t)(base + rl) * INTER + kbase + ((gq ^ sw) << 3);
        dstA[i] = i * 4096 + tid * 16;
    }
    int rb = tid >> 2;
    const float* srcB = w2 + ((size_t)e * HID + col0 + rb) * INTER + kbase + (gq << 3);
    int offB = rb * 64 + ((gq ^ sw) << 4);

    // ---- prologue ----
#pragma unroll
    for (int i = 0; i < 2; ++i) gload_lds16(srcA[i], (char*)As[0] + dstA[i]);
    {
        float4 b0 = *(const float4*)(srcB);
        float4 b1 = *(const float4*)(srcB + 4);
        *(bf16x8*)((char*)Bs[0] + offB) = cvt8(b0, b1);
    }
    __syncthreads();

    int wr = (wid >> 1) * 64, wc = (wid & 1) * 32;
    f32x4 acc[4][2] = {};

    for (int t = 0; t < 32; ++t) {
        int cur = t & 1;
        float4 b0, b1;
        bool pre = (t < 31);
        if (pre) {
            int k0 = (t + 1) * 32;
#pragma unroll
            for (int i = 0; i < 2; ++i)
                gload_lds16(srcA[i] + k0, (char*)As[cur ^ 1] + dstA[i]);
            b0 = *(const float4*)(srcB + k0);
            b1 = *(const float4*)(srcB + k0 + 4);
        }
        const __bf16* Ab = As[cur];
        const __bf16* Bb = Bs[cur];
        {
            int kg = lane >> 4;
            bf16x8 a[4], b[2];
#pragma unroll
            for (int m = 0; m < 4; ++m) a[m] = ldsfrag(Ab, wr + m * 16 + (lane & 15), kg);
#pragma unroll
            for (int n = 0; n < 2; ++n) b[n] = ldsfrag(Bb, wc + n * 16 + (lane & 15), kg);
#pragma unroll
            for (int m = 0; m < 4; ++m)
#pragma unroll
                for (int n = 0; n < 2; ++n)
                    acc[m][n] = __builtin_amdgcn_mfma_f32_16x16x32_bf16(a[m], b[n], acc[m][n], 0, 0, 0);
        }
        if (pre) {
            *(bf16x8*)((char*)Bs[cur ^ 1] + offB) = cvt8(b0, b1);
        }
        __syncthreads();
    }

    // epilogue: out[tok, col] += wgt * acc  (commutative fp32 adds; 4/elem)
#pragma unroll
    for (int m = 0; m < 4; ++m) {
#pragma unroll
        for (int j = 0; j < 4; ++j) {
            int rl = wr + m * 16 + ((lane >> 4) << 2) + j;
            if (row0 + rl >= cnt) continue;
            float wgt = row_w[base + row0 + rl];
            int tok = row_token[base + row0 + rl];
#pragma unroll
            for (int n = 0; n < 2; ++n)
                atomicAdd(&out[(size_t)tok * HID + col0 + wc + n * 16 + (lane & 15)],
                          acc[m][n][j] * wgt);
        }
    }
}

extern "C" void kernel_launch(void* const* d_in, const int* in_sizes, int n_in,
                              void* d_out, int out_size, void* d_ws, size_t ws_size,
                              hipStream_t stream) {
    const float* x  = (const float*)d_in[0];   // [1,2048,1024]
    const float* w1 = (const float*)d_in[1];   // [8,4096,1024]
    const float* w2 = (const float*)d_in[2];   // [8,1024,2048]
    const float* rw = (const float*)d_in[3];   // [8,1024]
    float* out = (float*)d_out;

    char* ws = (char*)d_ws;
    int*    counts     = (int*)(ws + WS_COUNTS);
    int*    offsets    = (int*)(ws + WS_OFFSETS);
    int*    sel        = (int*)(ws + WS_SEL);
    float*  selw       = (float*)(ws + WS_SELW);
    int*    row_token  = (int*)(ws + WS_ROWTOK);
    float*  row_w      = (float*)(ws + WS_ROWW);
    __bf16* xb         = (__bf16*)(ws + WS_XB);
    __bf16* y          = (__bf16*)(ws + WS_Y);

    hipMemsetAsync(ws, 0, 128, stream);
    hipMemsetAsync(out, 0, (size_t)T_TOKENS * HID * sizeof(float), stream);

    moe_router<<<T_TOKENS / 4, 256, 0, stream>>>(x, rw, counts, sel, selw, xb);
    moe_scan_assign<<<1, 256, 0, stream>>>(counts, offsets, sel, selw,
                                           row_token, row_w);
    moe_gemm1<<<dim3(INTER / 64, 16, NE), 256, 0, stream>>>(
        xb, w1, row_token, counts, offsets, y);
    moe_gemm2<<<dim3(HID / 64, 32, NE), 256, 0, stream>>>(
        y, w2, row_w, row_token, counts, offsets, out);
}

// Round 12
// 406.050 us; speedup vs baseline: 1.0436x; 1.0436x over previous
//
#include <hip/hip_runtime.h>
#include <hip/hip_bf16.h>
#include <math.h>

#define T_TOKENS 2048
#define HID 1024
#define INTER 2048
#define NE 8

typedef __attribute__((ext_vector_type(8))) __bf16 bf16x8;
typedef __attribute__((ext_vector_type(4))) __bf16 bf16x4;
typedef __attribute__((ext_vector_type(4))) float f32x4;

// ---------------- workspace layout (bytes) ----------------
#define WS_COUNTS   0u          // int[8]
#define WS_OFFSETS  64u         // int[8]
#define WS_SEL      128u        // int[4096]
#define WS_SELW     16512u      // float[4096]
#define WS_ROWTOK   32896u      // int[4096]
#define WS_ROWW     49280u      // float[4096]
#define WS_XB       131072u                      // bf16[2048*1024]  (4 MB)
#define WS_Y        (131072u + 4194304u)         // bf16[4096*2048]  (16.8 MB)

// async global->LDS, 16B per lane (dest = wave-uniform base + lane*16, m104)
__device__ __forceinline__ void gload_lds16(const void* g, void* l) {
    __builtin_amdgcn_global_load_lds(
        (const __attribute__((address_space(1))) unsigned int*)g,
        (__attribute__((address_space(3))) unsigned int*)l, 16, 0, 0);
}

__device__ __forceinline__ bf16x8 cvt8(float4 a, float4 b) {
    bf16x8 r;
    r[0] = (__bf16)a.x; r[1] = (__bf16)a.y; r[2] = (__bf16)a.z; r[3] = (__bf16)a.w;
    r[4] = (__bf16)b.x; r[5] = (__bf16)b.y; r[6] = (__bf16)b.z; r[7] = (__bf16)b.w;
    return r;
}

// A tile: bf16 [128][64], 128B rows, 8x 16B granules; swizzle g ^ (row&7)
// (verified R3-R6: SQ_LDS_BANK_CONFLICT == 0).
__device__ __forceinline__ bf16x8 ldsfragA(const __bf16* base, int row, int g) {
    return *(const bf16x8*)((const char*)base + row * 128 + ((g ^ (row & 7)) << 4));
}

// B tile: fp32 [rows][64], 256B rows, 16x 16B granules. K-slice kc4 (8 fp32) =
// granule pair (2*kc4, 2*kc4+1), each swizzled by row&7. Slot math: slot =
// (g ^ (row&7)) & 7 -> 16 lanes hit 8 slots x2 = free. Convert to bf16 here.
__device__ __forceinline__ bf16x8 ldsfragB(const float* base, int row, int kc4) {
    const char* p = (const char*)base + row * 256;
    int s = row & 7;
    float4 p0 = *(const float4*)(p + ((((kc4 << 1)    ) ^ s) << 4));
    float4 p1 = *(const float4*)(p + ((((kc4 << 1) | 1) ^ s) << 4));
    return cvt8(p0, p1);
}

// ---------------- router (exact fp32) + fused x->bf16 conversion ----------------
__global__ __launch_bounds__(256) void moe_router(
    const float* __restrict__ x, const float* __restrict__ rw,
    int* __restrict__ counts, int* __restrict__ sel, float* __restrict__ selw,
    __bf16* __restrict__ xb)
{
    int wave = threadIdx.x >> 6;
    int lane = threadIdx.x & 63;
    int t = blockIdx.x * 4 + wave;
    if (t >= T_TOKENS) return;

    const float4* x4  = (const float4*)x + (size_t)t * (HID / 4);
    const float4* rw4 = (const float4*)rw;

    float acc[NE];
#pragma unroll
    for (int e = 0; e < NE; ++e) acc[e] = 0.f;
#pragma unroll
    for (int q = 0; q < 4; ++q) {
        int idx = q * 64 + lane;
        float4 xv = x4[idx];
        bf16x4 c;
        c[0] = (__bf16)xv.x; c[1] = (__bf16)xv.y; c[2] = (__bf16)xv.z; c[3] = (__bf16)xv.w;
        *(bf16x4*)(xb + (size_t)t * HID + idx * 4) = c;
#pragma unroll
        for (int e = 0; e < NE; ++e) {
            float4 rv = rw4[e * (HID / 4) + idx];
            acc[e] += xv.x * rv.x + xv.y * rv.y + xv.z * rv.z + xv.w * rv.w;
        }
    }
#pragma unroll
    for (int off = 32; off; off >>= 1)
#pragma unroll
        for (int e = 0; e < NE; ++e) acc[e] += __shfl_xor(acc[e], off, 64);

    if (lane == 0) {
        float m = acc[0];
#pragma unroll
        for (int e = 1; e < NE; ++e) m = fmaxf(m, acc[e]);
        float p[NE], s = 0.f;
#pragma unroll
        for (int e = 0; e < NE; ++e) { p[e] = expf(acc[e] - m); s += p[e]; }
        float inv = 1.f / s;
        int i0 = 0;
#pragma unroll
        for (int e = 1; e < NE; ++e) if (p[e] > p[i0]) i0 = e;
        int i1 = (i0 == 0) ? 1 : 0;
#pragma unroll
        for (int e = 0; e < NE; ++e) if (e != i0 && p[e] > p[i1]) i1 = e;
        sel[t * 2 + 0] = i0; selw[t * 2 + 0] = p[i0] * inv;
        sel[t * 2 + 1] = i1; selw[t * 2 + 1] = p[i1] * inv;
        atomicAdd(&counts[i0], 1);
        atomicAdd(&counts[i1], 1);
    }
}

// ---------------- fused scan + slot assignment (single block) ----------------
__global__ __launch_bounds__(256) void moe_scan_assign(
    const int* __restrict__ counts, int* __restrict__ offsets,
    const int* __restrict__ sel, const float* __restrict__ selw,
    int* __restrict__ row_token, float* __restrict__ row_w)
{
    __shared__ int soff[NE];
    __shared__ int scur[NE];
    if (threadIdx.x == 0) {
        int off = 0;
        for (int e = 0; e < NE; ++e) { soff[e] = off; off += counts[e]; }
    }
    if (threadIdx.x < NE) scur[threadIdx.x] = 0;
    __syncthreads();
    if (threadIdx.x < NE) offsets[threadIdx.x] = soff[threadIdx.x];
    for (int t = threadIdx.x; t < T_TOKENS; t += 256) {
#pragma unroll
        for (int k = 0; k < 2; ++k) {
            int e = sel[t * 2 + k];
            int slot = atomicAdd(&scur[e], 1);
            int r = soff[e] + slot;
            row_token[r] = t;
            row_w[r] = selw[t * 2 + k];
        }
    }
}

// ---------------- GEMM1: m97-structure (gload_lds A bf16 + B fp32 direct) -------
// tile 128 rows x 64 y-cols; B-tile = 128 rows (64 gate + 64 up) x BK=64 fp32.
// LDS 16KB + 32KB = 48KB -> 3 blocks/CU. Per wave per step: 32 MFMA.
__global__ __launch_bounds__(256, 3) void moe_gemm1(
    const __bf16* __restrict__ xb, const float* __restrict__ w1,
    const int* __restrict__ row_token, const int* __restrict__ counts,
    const int* __restrict__ offsets, __bf16* __restrict__ y)
{
    int e = blockIdx.z;
    int cnt = counts[e];
    int row0 = blockIdx.y * 128;
    if (row0 >= cnt) return;
    int col0 = blockIdx.x * 64;
    int base = offsets[e];

    __shared__ __bf16 As[128 * 64];      // 16 KB
    __shared__ float  Bs[128 * 64];      // 32 KB (rows 0-63 gate, 64-127 up)

    int tid = threadIdx.x;
    int lane = tid & 63;
    int wid = tid >> 6;

    // ---- A staging map (verified R3-R6): gload i covers rows ii*8..+7 ----
    const __bf16* srcA[4];
    int dstA[4];
#pragma unroll
    for (int i = 0; i < 4; ++i) {
        int ii = wid * 4 + i;
        int r = ii * 8 + (lane >> 3);
        int rl = row0 + r; if (rl > cnt - 1) rl = cnt - 1;
        int tok = row_token[base + rl];
        srcA[i] = xb + (size_t)tok * HID + (((lane & 7) ^ (r & 7)) << 3);
        dstA[i] = ii * 1024 + lane * 16;
    }
    // ---- B staging map: gload i covers rows wid*32+i*4 .. +3 (4 rows x 256B) --
    // r&7 parity alternates with i: two base ptrs (even/odd i), + (i>>1)*8 rows.
    const float* srcB[2];   // [parity]
    int dstB0 = wid * 8192 + lane * 16;  // i=0 base; + i*1024 per gload
    {
        int rev = wid * 32 + (lane >> 4);          // i=0 row
        int rod = rev + 4;                          // i=1 row
        int grow_ev = (rev < 64) ? (col0 + rev) : (INTER + col0 + rev - 64);
        int grow_od = (rod < 64) ? (col0 + rod) : (INTER + col0 + rod - 64);
        srcB[0] = w1 + ((size_t)e * 2 * INTER + grow_ev) * HID
                     + (((lane & 15) ^ (rev & 7)) << 2);
        srcB[1] = w1 + ((size_t)e * 2 * INTER + grow_od) * HID
                     + (((lane & 15) ^ (rod & 7)) << 2);
    }

    int wr = (wid >> 1) * 64, wc = (wid & 1) * 32;
    f32x4 ag[4][2] = {}, au[4][2] = {};

    for (int k0 = 0; k0 < HID; k0 += 64) {
        __syncthreads();                          // prior compute done
#pragma unroll
        for (int i = 0; i < 4; ++i)
            gload_lds16(srcA[i] + k0, (char*)As + dstA[i]);
#pragma unroll
        for (int i = 0; i < 8; ++i)
            gload_lds16(srcB[i & 1] + (i >> 1) * (8 * HID) + k0,
                        (char*)Bs + dstB0 + i * 1024);
        __syncthreads();                          // drains vmcnt -> LDS ready
#pragma unroll
        for (int ks = 0; ks < 2; ++ks) {
            int kc4 = ks * 4 + (lane >> 4);
            bf16x8 a[4], bg[2], bu[2];
#pragma unroll
            for (int m = 0; m < 4; ++m) a[m] = ldsfragA(As, wr + m * 16 + (lane & 15), kc4);
#pragma unroll
            for (int n = 0; n < 2; ++n) {
                bg[n] = ldsfragB(Bs, wc + n * 16 + (lane & 15), kc4);
                bu[n] = ldsfragB(Bs, 64 + wc + n * 16 + (lane & 15), kc4);
            }
#pragma unroll
            for (int m = 0; m < 4; ++m)
#pragma unroll
                for (int n = 0; n < 2; ++n) {
                    ag[m][n] = __builtin_amdgcn_mfma_f32_16x16x32_bf16(a[m], bg[n], ag[m][n], 0, 0, 0);
                    au[m][n] = __builtin_amdgcn_mfma_f32_16x16x32_bf16(a[m], bu[n], au[m][n], 0, 0, 0);
                }
        }
    }

    // epilogue: silu(g)*u -> bf16 y.  D layout: col=lane&15, row=(lane>>4)*4+j
#pragma unroll
    for (int m = 0; m < 4; ++m) {
#pragma unroll
        for (int j = 0; j < 4; ++j) {
            int rl = wr + m * 16 + ((lane >> 4) << 2) + j;
            if (row0 + rl >= cnt) continue;
            size_t yrow = (size_t)(base + row0 + rl) * INTER;
#pragma unroll
            for (int n = 0; n < 2; ++n) {
                float g = ag[m][n][j], u = au[m][n][j];
                float s = g / (1.f + __expf(-g));
                y[yrow + col0 + wc + n * 16 + (lane & 15)] = (__bf16)(s * u);
            }
        }
    }
}

// ---------------- GEMM2: m97-structure + split-K=4, fused atomic combine --------
// tile 128 rows x 128 HID-cols; BK=64; K-range 512 per split. LDS 48KB.
__global__ __launch_bounds__(256, 3) void moe_gemm2(
    const __bf16* __restrict__ y, const float* __restrict__ w2,
    const float* __restrict__ row_w, const int* __restrict__ row_token,
    const int* __restrict__ counts, const int* __restrict__ offsets,
    float* __restrict__ out)
{
    int e = blockIdx.z;
    int cnt = counts[e];
    int row0 = (blockIdx.y >> 2) * 128;
    if (row0 >= cnt) return;
    int kbase = (blockIdx.y & 3) * (INTER / 4);
    int col0 = blockIdx.x * 128;
    int base = offsets[e];

    __shared__ __bf16 As[128 * 64];      // 16 KB
    __shared__ float  Bs[128 * 64];      // 32 KB (128 HID-cols)

    int tid = threadIdx.x;
    int lane = tid & 63;
    int wid = tid >> 6;

    const __bf16* srcA[4];
    int dstA[4];
#pragma unroll
    for (int i = 0; i < 4; ++i) {
        int ii = wid * 4 + i;
        int r = ii * 8 + (lane >> 3);
        int rl = row0 + r; if (rl > cnt - 1) rl = cnt - 1;
        srcA[i] = y + (size_t)(base + rl) * INTER + kbase + (((lane & 7) ^ (r & 7)) << 3);
        dstA[i] = ii * 1024 + lane * 16;
    }
    const float* srcB[2];
    int dstB0 = wid * 8192 + lane * 16;
    {
        int rev = wid * 32 + (lane >> 4);
        int rod = rev + 4;
        srcB[0] = w2 + ((size_t)e * HID + col0 + rev) * INTER + kbase
                     + (((lane & 15) ^ (rev & 7)) << 2);
        srcB[1] = w2 + ((size_t)e * HID + col0 + rod) * INTER + kbase
                     + (((lane & 15) ^ (rod & 7)) << 2);
    }

    int wr = (wid >> 1) * 64, wc = (wid & 1) * 64;
    f32x4 acc[4][4] = {};

    for (int k0 = 0; k0 < INTER / 4; k0 += 64) {
        __syncthreads();
#pragma unroll
        for (int i = 0; i < 4; ++i)
            gload_lds16(srcA[i] + k0, (char*)As + dstA[i]);
#pragma unroll
        for (int i = 0; i < 8; ++i)
            gload_lds16(srcB[i & 1] + (i >> 1) * (8 * INTER) + k0,
                        (char*)Bs + dstB0 + i * 1024);
        __syncthreads();
#pragma unroll
        for (int ks = 0; ks < 2; ++ks) {
            int kc4 = ks * 4 + (lane >> 4);
            bf16x8 a[4], b[4];
#pragma unroll
            for (int m = 0; m < 4; ++m) a[m] = ldsfragA(As, wr + m * 16 + (lane & 15), kc4);
#pragma unroll
            for (int n = 0; n < 4; ++n) b[n] = ldsfragB(Bs, wc + n * 16 + (lane & 15), kc4);
#pragma unroll
            for (int m = 0; m < 4; ++m)
#pragma unroll
                for (int n = 0; n < 4; ++n)
                    acc[m][n] = __builtin_amdgcn_mfma_f32_16x16x32_bf16(a[m], b[n], acc[m][n], 0, 0, 0);
        }
    }

    // epilogue: out[tok, col] += wgt * acc  (commutative fp32 adds; 8/elem)
#pragma unroll
    for (int m = 0; m < 4; ++m) {
#pragma unroll
        for (int j = 0; j < 4; ++j) {
            int rl = wr + m * 16 + ((lane >> 4) << 2) + j;
            if (row0 + rl >= cnt) continue;
            float wgt = row_w[base + row0 + rl];
            int tok = row_token[base + row0 + rl];
#pragma unroll
            for (int n = 0; n < 4; ++n)
                atomicAdd(&out[(size_t)tok * HID + col0 + wc + n * 16 + (lane & 15)],
                          acc[m][n][j] * wgt);
        }
    }
}

extern "C" void kernel_launch(void* const* d_in, const int* in_sizes, int n_in,
                              void* d_out, int out_size, void* d_ws, size_t ws_size,
                              hipStream_t stream) {
    const float* x  = (const float*)d_in[0];   // [1,2048,1024]
    const float* w1 = (const float*)d_in[1];   // [8,4096,1024]
    const float* w2 = (const float*)d_in[2];   // [8,1024,2048]
    const float* rw = (const float*)d_in[3];   // [8,1024]
    float* out = (float*)d_out;

    char* ws = (char*)d_ws;
    int*    counts     = (int*)(ws + WS_COUNTS);
    int*    offsets    = (int*)(ws + WS_OFFSETS);
    int*    sel        = (int*)(ws + WS_SEL);
    float*  selw       = (float*)(ws + WS_SELW);
    int*    row_token  = (int*)(ws + WS_ROWTOK);
    float*  row_w      = (float*)(ws + WS_ROWW);
    __bf16* xb         = (__bf16*)(ws + WS_XB);
    __bf16* y          = (__bf16*)(ws + WS_Y);

    hipMemsetAsync(ws, 0, 128, stream);
    hipMemsetAsync(out, 0, (size_t)T_TOKENS * HID * sizeof(float), stream);

    moe_router<<<T_TOKENS / 4, 256, 0, stream>>>(x, rw, counts, sel, selw, xb);
    moe_scan_assign<<<1, 256, 0, stream>>>(counts, offsets, sel, selw,
                                           row_token, row_w);
    moe_gemm1<<<dim3(INTER / 64, 16, NE), 256, 0, stream>>>(
        xb, w1, row_token, counts, offsets, y);
    moe_gemm2<<<dim3(HID / 128, 64, NE), 256, 0, stream>>>(
        y, w2, row_w, row_token, counts, offsets, out);
}